// Round 7
// baseline (296.688 us; speedup 1.0000x reference)
//
#include <hip/hip_runtime.h>

#define TOK 65536
#define DM 256
#define DF 1024
#define NB 4

typedef unsigned short ushort_t;
typedef unsigned int uint32;

typedef __attribute__((ext_vector_type(8))) short bf16x8;
typedef __attribute__((ext_vector_type(4))) float f32x4;
typedef __attribute__((ext_vector_type(4))) uint32 u32x4;

__device__ inline ushort_t f2bf(float f) {
  union { float f; unsigned int u; } v; v.f = f;
  unsigned int u = v.u;
  unsigned int r = (u + 0x7FFFu + ((u >> 16) & 1u)) >> 16;
  return (ushort_t)r;
}
__device__ inline float bf2f(ushort_t u) {
  union { unsigned int u; float f; } v; v.u = ((uint32)u) << 16; return v.f;
}
__device__ inline uint32 pack2(float a, float b) {
  return (uint32)f2bf(a) | ((uint32)f2bf(b) << 16);
}

// async global->LDS DMA, 16 B/lane: LDS dest = wave-uniform base + lane*16.
__device__ __forceinline__ void dma16(const ushort_t* g, ushort_t* lds) {
  __builtin_amdgcn_global_load_lds(
      (const __attribute__((address_space(1))) unsigned int*)(const void*)g,
      (__attribute__((address_space(3))) unsigned int*)(void*)lds,
      16, 0, 0);
}

// ------- kernel 0: merged route + W1 bf16 convert + W2 frag-layout ---------
// blocks [0,256): route (counts pre-zeroed via hipMemsetAsync)
// blocks [256,1280): W1 fp32 -> bf16 plain row-major (DMA-staged in ffn)
// blocks [1280,1792): W2 fp32 -> bf16 FRAGMENT layout (direct reg loads):
//  W2f[((fc*4+dq)*4+di)*512 + lane*8 + j] (per branch) =
//      W2[n][dq*64+di*16+(lane&15)][fc*32+(lane>>4)*8+j]
__global__ __launch_bounds__(256) void prep_route_kernel(
    const float* __restrict__ w1, const float* __restrict__ w2,
    ushort_t* __restrict__ w1b, ushort_t* __restrict__ w2fb,
    const int* __restrict__ b_seq, int* __restrict__ counts,
    ushort_t* __restrict__ lists, u32x4* __restrict__ out16)
{
  const int bx = blockIdx.x;
  const int tid = threadIdx.x;
  if (bx >= 1280) {
    // ---- W2 fragment-layout conversion (verified in round 6)
    const int gid = (bx - 1280) * 256 + tid;   // 0..131071
    const int lane_ = gid & 63;
    const int lcq = lane_ & 15, qq = lane_ >> 4;
    int di = (gid >> 6) & 3, dqv = (gid >> 8) & 3;
    int fc = (gid >> 10) & 31, nn = gid >> 15;
    size_t src_off = (size_t)(nn * 256 + dqv * 64 + di * 16 + lcq) * 1024 + fc * 32 + qq * 8;
    const float* src = w2 + src_off;
    f32x4 a = *(const f32x4*)src;
    f32x4 c = *(const f32x4*)(src + 4);
    u32x4 p;
    p.x = pack2(a.x, a.y); p.y = pack2(a.z, a.w);
    p.z = pack2(c.x, c.y); p.w = pack2(c.z, c.w);
    *(u32x4*)(w2fb + (size_t)gid * 8) = p;
    return;
  }
  if (bx >= 256) {
    // ---- W1 plain bf16 conversion
    const int idx = (bx - 256) * 256 + tid;
    f32x4 v = *(const f32x4*)(w1 + (size_t)idx * 4);
    uint2 p;
    p.x = pack2(v.x, v.y);
    p.y = pack2(v.z, v.w);
    *(uint2*)(w1b + (size_t)idx * 4) = p;
    return;
  }
  // ---- route branch
  __shared__ int s_lpos[NB];
  __shared__ int s_lbase[NB];
  __shared__ int s_b[256];
  const int base = bx * 256;
  const int token = base + tid;
  if (tid < NB) s_lpos[tid] = 0;
  __syncthreads();
  const int b = b_seq[token];
  s_b[tid] = b;
  int my = 0;
  if (b > 0) my = atomicAdd(&s_lpos[b - 1], 1);
  __syncthreads();
  if (tid < NB) s_lbase[tid] = atomicAdd(&counts[tid], s_lpos[tid]);
  __syncthreads();
  if (b > 0) lists[(b - 1) * TOK + s_lbase[b - 1] + my] = (ushort_t)token;
  const u32x4 z = (u32x4){0u, 0u, 0u, 0u};
  #pragma unroll 4
  for (int it = 0; it < 64; ++it) {
    int flat = it * 256 + tid;
    int tl = flat >> 6;
    int j = flat & 63;
    if (s_b[tl] == 0) out16[(size_t)(base + tl) * 64 + j] = z;
  }
}

// ---------------- kernel 1: hybrid FFN + LN ---------------------------------
// Round-5 (121us): LDS pipe carried ~65% of cycles (112 b128 reads + 32KB DMA
// writes per chunk). Round-6: all-direct-L2 failed (no W1 prefetch depth, M=32
// residency loss). HYBRID: W1 stays DMA->LDS (4x read reuse); W2 moves to
// direct-from-L2 register prefetch (only 2x reuse; its 32 reads + 16KB of DMA
// writes leave the LDS pipe). W2 frags are loaded one full chunk-interval
// (~600cy) before consumption -> L2 latency covered, unlike round 6.
// Block = 8 waves (512 thr), M=64 tokens, 32 chunks of F=32. Same proven
// round-5 barrier scheme: one vmcnt(0)+lgkm(0) barrier per chunk.
//  GEMM1 wave (fi=wv&1, mq=wv>>1): 16 tok x 16 f; xfrag[8]=32 VGPR.
//  GEMM2 wave (dq=wv&3, mh=wv>>2): 32 tok x 64 d; yacc[2][4]=32 AGPR;
//    W2 frags double-buffered in regs (w2A/w2B, 16 VGPR each, 2-unrolled).
// LDS reads/chunk: 80 b128 (was 112); DMA writes 16KB (was 32KB).
__global__ __launch_bounds__(512, 4) void ffn_kernel(
    const float* __restrict__ x,
    const ushort_t* __restrict__ w1b_all, const float* __restrict__ b1,
    const ushort_t* __restrict__ w2f_all, const float* __restrict__ b2,
    const float* __restrict__ gamma, const float* __restrict__ beta,
    const int* __restrict__ counts, const ushort_t* __restrict__ lists,
    float* __restrict__ out)
{
  const int id = blockIdx.x;
  const int slot = id & 7;            // XCD affinity: branch n -> XCDs {2n,2n+1}
  const int n = slot >> 1;
  const int tile = ((id >> 3) << 1) + (slot & 1);
  const int cnt = counts[n];
  const int tile0 = tile * 64;
  if (tile0 >= cnt) return;           // block-uniform exit before any barrier
  const int mvalid = min(64, cnt - tile0);

  __shared__ __align__(16) ushort_t sW1[2][8192];   // 2 x 16KB (32f x 256k)
  __shared__ __align__(16) ushort_t sH[2][64][40];  // H double-buffer
  __shared__ ushort_t sB1[DF];        // b1 as bf16 (exact for b1==0)
  __shared__ int s_idx[64];
  __shared__ float s_ps[4][64];
  __shared__ float s_pq[4][64];
  __shared__ float s_mu[64];
  __shared__ float s_rs[64];
  // total ~48 KB

  ushort_t (*sX)[256] = (ushort_t (*)[256])&sW1[0][0];  // prologue alias 32KB

  const int tid  = threadIdx.x;
  const int wv   = tid >> 6;          // 0..7
  const int lane = tid & 63;
  const int q    = lane >> 4;
  const int lc   = lane & 15;
  const int fi   = wv & 1;            // GEMM1: f-sub (16 of the 32-chunk)
  const int mq   = wv >> 1;           // GEMM1: token quarter (16 rows)
  const int dq   = wv & 3;            // GEMM2: d-quarter (64 cols)
  const int mh   = wv >> 2;           // GEMM2: token half (32 rows)

  const ushort_t* w1b = w1b_all + (size_t)n * DF * DM;
  const ushort_t* w2f = w2f_all + (size_t)n * 262144;   // 512 KB / branch

  if (tid < 64) {
    int i = tile0 + tid;
    s_idx[tid] = (int)lists[n * TOK + (i < cnt ? i : tile0)];
  }
  if (tid < 256) {
    f32x4 v = *(const f32x4*)(b1 + n * DF + tid * 4);
    uint2 p;
    p.x = pack2(v.x, v.y);
    p.y = pack2(v.z, v.w);
    *(uint2*)(sB1 + tid * 4) = p;
  }
  __syncthreads();                    // B0: s_idx ready

  // ---- stage X tile 64x256 fp32 -> bf16 into sX, 16B-granule XOR swizzle
  #pragma unroll
  for (int it = 0; it < 4; ++it) {
    int flat = it * 512 + tid;
    int r = flat >> 5;                 // 0..63
    int c8 = flat & 31;                // 16B granule (8 bf16)
    const float* xp = x + (size_t)s_idx[r] * DM + c8 * 8;
    f32x4 a = *(const f32x4*)xp;
    f32x4 c = *(const f32x4*)(xp + 4);
    u32x4 p;
    p.x = pack2(a.x, a.y); p.y = pack2(a.z, a.w);
    p.z = pack2(c.x, c.y); p.w = pack2(c.z, c.w);
    *(u32x4*)(&sX[r][(c8 ^ (r & 31)) * 8]) = p;
  }
  __syncthreads();                    // B1: sX ready

  // ---- X A-frags to regs: this wave's 16 tokens x K=256 (32 VGPR)
  bf16x8 xfrag[8];
  #pragma unroll
  for (int ks = 0; ks < 8; ++ks) {
    int row = mq * 16 + lc;
    int g = (ks * 4 + q) ^ (row & 31);
    xfrag[ks] = *(const bf16x8*)(&sX[row][g * 8]);
  }
  __syncthreads();                    // B2: sX dead, W1 bufs free

  // W1 chunk fc -> sW1[fc&1]: 16 x 1KB segs over 8 waves (2/wave).
  // LDS[r][c] = G[r][c ^ r] (src-side swizzle; matches GEMM1 read).
  auto issue_w1 = [&](int fc) {
    ushort_t* dst = sW1[fc & 1];
    const ushort_t* g1p = w1b + (size_t)(fc * 32) * DM;
    #pragma unroll
    for (int j = 0; j < 2; ++j) {
      int i = wv * 2 + j;              // 0..15
      int s = i * 64 + lane;
      int r1 = s >> 5, cp1 = s & 31;
      dma16(g1p + (size_t)r1 * DM + (size_t)(cp1 ^ r1) * 8, dst + i * 512);
    }
  };
  // W2 chunk fc -> this wave's 4 frags (4KB, coalesced dwordx4 from L2)
  auto w2load = [&](int fc, bf16x8 (&w2r)[4]) {
    const ushort_t* p = w2f + (size_t)(fc * 4 + dq) * 2048 + lane * 8;
    #pragma unroll
    for (int di = 0; di < 4; ++di)
      w2r[di] = *(const bf16x8*)(p + di * 512);
  };

  f32x4 yacc[2][4];       // [mi2][di]: 32 tok x 64 d (32 AGPR)
  #pragma unroll
  for (int mi2 = 0; mi2 < 2; ++mi2)
    #pragma unroll
    for (int di = 0; di < 4; ++di)
      yacc[mi2][di] = (f32x4){0.f, 0.f, 0.f, 0.f};

  const int r1row = fi * 16 + lc;     // GEMM1 W1 local row (0..31)

  auto ebar = [&]() {
    __builtin_amdgcn_sched_barrier(0);
    __builtin_amdgcn_s_waitcnt(0x0070);     // vmcnt(0) lgkmcnt(0)
    __builtin_amdgcn_s_barrier();
    __builtin_amdgcn_sched_barrier(0);
  };
  auto g1 = [&](int fc) {
    const ushort_t* w1row = sW1[fc & 1] + r1row * 256;
    const float b1v = bf2f(sB1[fc * 32 + fi * 16 + lc]);
    f32x4 ha = (f32x4){0.f, 0.f, 0.f, 0.f};
    f32x4 hb = (f32x4){0.f, 0.f, 0.f, 0.f};
    __builtin_amdgcn_s_setprio(1);
    #pragma unroll
    for (int ks = 0; ks < 4; ++ks) {
      int cpa = ((2 * ks) * 4 + q) ^ r1row;
      int cpb = ((2 * ks + 1) * 4 + q) ^ r1row;
      bf16x8 bfa = *(const bf16x8*)(w1row + cpa * 8);
      bf16x8 bfb = *(const bf16x8*)(w1row + cpb * 8);
      ha = __builtin_amdgcn_mfma_f32_16x16x32_bf16(xfrag[2 * ks],     bfa, ha, 0, 0, 0);
      hb = __builtin_amdgcn_mfma_f32_16x16x32_bf16(xfrag[2 * ks + 1], bfb, hb, 0, 0, 0);
    }
    __builtin_amdgcn_s_setprio(0);
    #pragma unroll
    for (int r4 = 0; r4 < 4; ++r4) {
      float v = ha[r4] + hb[r4] + b1v;
      v = (v > 0.f) ? v : (__expf(v) - 1.f);
      sH[fc & 1][mq * 16 + q * 4 + r4][fi * 16 + lc] = f2bf(v);
    }
  };
  auto g2_comp = [&](int fc, bf16x8 (&w2r)[4]) {
    const int rb = fc & 1;
    bf16x8 af0 = *(const bf16x8*)(&sH[rb][mh * 32 + lc][q * 8]);
    bf16x8 af1 = *(const bf16x8*)(&sH[rb][mh * 32 + 16 + lc][q * 8]);
    __builtin_amdgcn_s_setprio(1);
    #pragma unroll
    for (int di = 0; di < 4; ++di) {
      yacc[0][di] = __builtin_amdgcn_mfma_f32_16x16x32_bf16(af0, w2r[di], yacc[0][di], 0, 0, 0);
      yacc[1][di] = __builtin_amdgcn_mfma_f32_16x16x32_bf16(af1, w2r[di], yacc[1][di], 0, 0, 0);
    }
    __builtin_amdgcn_s_setprio(0);
  };

  bf16x8 w2A[4], w2B[4];

  // Pipeline (2-unrolled for static reg-buffer naming, rule #20):
  // iter i: ebar -> issue W1(i+1) DMA, load W2(i) regs, GEMM1(i), GEMM2(i-1).
  // W2(i) regs are consumed at iter i+1 (one full chunk-interval of cover).
  issue_w1(0);
  ebar();                              // drain W1(0) (startup, uncovered)
  issue_w1(1);
  w2load(0, w2A);
  g1(0);
  #pragma unroll 1
  for (int i = 1; i < 32; i += 2) {
    ebar();
    if (i < 31) issue_w1(i + 1);       // even chunks 2..30
    w2load(i, w2B);
    g1(i);
    g2_comp(i - 1, w2A);
    ebar();
    if (i < 30) issue_w1(i + 2);       // odd chunks 3..31
    if (i + 1 < 32) w2load(i + 1, w2A);
    if (i + 1 < 32) g1(i + 1);
    g2_comp(i, w2B);
  }

  // ================= epilogue: +b2, LN stats, gamma/beta, store =============
  __syncthreads();
  float b2v[4], gv[4], bv[4];
  #pragma unroll
  for (int di = 0; di < 4; ++di) {
    int dcol = n * DM + dq * 64 + di * 16 + lc;
    b2v[di] = b2[dcol];
    gv[di]  = gamma[dcol];
    bv[di]  = beta[dcol];
  }
  #pragma unroll
  for (int mi2 = 0; mi2 < 2; ++mi2)
    #pragma unroll
    for (int di = 0; di < 4; ++di)
      #pragma unroll
      for (int r4 = 0; r4 < 4; ++r4)
        yacc[mi2][di][r4] += b2v[di];

  #pragma unroll
  for (int mi2 = 0; mi2 < 2; ++mi2) {
    #pragma unroll
    for (int r4 = 0; r4 < 4; ++r4) {
      float s = 0.f, sq = 0.f;
      #pragma unroll
      for (int di = 0; di < 4; ++di) {
        float v = yacc[mi2][di][r4];
        s += v; sq += v * v;
      }
      #pragma unroll
      for (int off = 1; off < 16; off <<= 1) {
        s  += __shfl_xor(s, off, 64);
        sq += __shfl_xor(sq, off, 64);
      }
      if (lc == 0) {
        int tok = mh * 32 + mi2 * 16 + q * 4 + r4;
        s_ps[dq][tok] = s;
        s_pq[dq][tok] = sq;
      }
    }
  }
  __syncthreads();
  if (tid < 64) {
    float s  = s_ps[0][tid] + s_ps[1][tid] + s_ps[2][tid] + s_ps[3][tid];
    float sq = s_pq[0][tid] + s_pq[1][tid] + s_pq[2][tid] + s_pq[3][tid];
    float mu = s * (1.f / 256.f);
    float var = fmaxf(sq * (1.f / 256.f) - mu * mu, 0.f);
    s_mu[tid] = mu;
    s_rs[tid] = rsqrtf(var + 1e-12f);
  }
  __syncthreads();

  #pragma unroll
  for (int mi2 = 0; mi2 < 2; ++mi2) {
    #pragma unroll
    for (int r4 = 0; r4 < 4; ++r4) {
      int tok = mh * 32 + mi2 * 16 + q * 4 + r4;
      if (tok < mvalid) {
        float mu = s_mu[tok], rs = s_rs[tok];
        size_t rowbase = (size_t)s_idx[tok] * DM + dq * 64;
        #pragma unroll
        for (int di = 0; di < 4; ++di) {
          float v = (yacc[mi2][di][r4] - mu) * rs * gv[di] + bv[di];
          out[rowbase + di * 16 + lc] = v;
        }
      }
    }
  }
}

extern "C" void kernel_launch(void* const* d_in, const int* in_sizes, int n_in,
                              void* d_out, int out_size, void* d_ws, size_t ws_size,
                              hipStream_t stream) {
  const float* x     = (const float*)d_in[0];
  const int*   b_seq = (const int*)d_in[1];
  const float* w1    = (const float*)d_in[2];
  const float* b1    = (const float*)d_in[3];
  const float* w2    = (const float*)d_in[4];
  const float* b2    = (const float*)d_in[5];
  const float* gamma = (const float*)d_in[6];
  const float* beta  = (const float*)d_in[7];
  float* out = (float*)d_out;

  int* counts = (int*)d_ws;
  ushort_t* lists = (ushort_t*)((char*)d_ws + 256);                 // 512 KB
  ushort_t* w1b = (ushort_t*)((char*)d_ws + 256 + 512 * 1024);      // 2 MB
  ushort_t* w2fb = w1b + (size_t)NB * DF * DM;                      // 2 MB

  hipMemsetAsync(counts, 0, 256, stream);
  // blocks [0,256): route; [256,1280): W1 bf16; [1280,1792): W2 frag layout
  hipLaunchKernelGGL(prep_route_kernel, dim3(1792), dim3(256), 0, stream,
                     w1, w2, w1b, w2fb, b_seq, counts, lists, (u32x4*)d_out);
  // 1024 tiles/branch capacity: covers any branch imbalance up to 65536
  hipLaunchKernelGGL(ffn_kernel, dim3(4096), dim3(512), 0, stream,
                     x, w1b, b1, w2fb, b2, gamma, beta, counts, lists, out);
}

// Round 8
// 214.550 us; speedup vs baseline: 1.3828x; 1.3828x over previous
//
#include <hip/hip_runtime.h>

#define TOK 65536
#define DM 256
#define DF 1024
#define NB 4

typedef unsigned short ushort_t;
typedef unsigned int uint32;

typedef __attribute__((ext_vector_type(8))) short bf16x8;
typedef __attribute__((ext_vector_type(4))) float f32x4;
typedef __attribute__((ext_vector_type(4))) uint32 u32x4;

__device__ inline ushort_t f2bf(float f) {
  union { float f; unsigned int u; } v; v.f = f;
  unsigned int u = v.u;
  unsigned int r = (u + 0x7FFFu + ((u >> 16) & 1u)) >> 16;
  return (ushort_t)r;
}
__device__ inline float bf2f(ushort_t u) {
  union { unsigned int u; float f; } v; v.u = ((uint32)u) << 16; return v.f;
}
__device__ inline uint32 pack2(float a, float b) {
  return (uint32)f2bf(a) | ((uint32)f2bf(b) << 16);
}

// async global->LDS DMA, 16 B/lane: LDS dest = wave-uniform base + lane*16.
__device__ __forceinline__ void dma16(const ushort_t* g, ushort_t* lds) {
  __builtin_amdgcn_global_load_lds(
      (const __attribute__((address_space(1))) unsigned int*)(const void*)g,
      (__attribute__((address_space(3))) unsigned int*)(void*)lds,
      16, 0, 0);
}

// ------- kernel 0: merged route + W1 bf16 convert + W2 frag-layout ---------
// blocks [0,256): route (counts pre-zeroed via hipMemsetAsync)
// blocks [256,1280): W1 fp32 -> bf16 plain row-major (DMA-staged in ffn)
// blocks [1280,1792): W2 fp32 -> bf16 FRAGMENT layout (direct reg loads):
//  W2f[((fc*4+dq)*4+di)*512 + lane*8 + j] (per branch) =
//      W2[n][dq*64+di*16+(lane&15)][fc*32+(lane>>4)*8+j]
__global__ __launch_bounds__(256) void prep_route_kernel(
    const float* __restrict__ w1, const float* __restrict__ w2,
    ushort_t* __restrict__ w1b, ushort_t* __restrict__ w2fb,
    const int* __restrict__ b_seq, int* __restrict__ counts,
    ushort_t* __restrict__ lists, u32x4* __restrict__ out16)
{
  const int bx = blockIdx.x;
  const int tid = threadIdx.x;
  if (bx >= 1280) {
    // ---- W2 fragment-layout conversion (verified rounds 6/7)
    const int gid = (bx - 1280) * 256 + tid;   // 0..131071
    const int lane_ = gid & 63;
    const int lcq = lane_ & 15, qq = lane_ >> 4;
    int di = (gid >> 6) & 3, dqv = (gid >> 8) & 3;
    int fc = (gid >> 10) & 31, nn = gid >> 15;
    size_t src_off = (size_t)(nn * 256 + dqv * 64 + di * 16 + lcq) * 1024 + fc * 32 + qq * 8;
    const float* src = w2 + src_off;
    f32x4 a = *(const f32x4*)src;
    f32x4 c = *(const f32x4*)(src + 4);
    u32x4 p;
    p.x = pack2(a.x, a.y); p.y = pack2(a.z, a.w);
    p.z = pack2(c.x, c.y); p.w = pack2(c.z, c.w);
    *(u32x4*)(w2fb + (size_t)gid * 8) = p;
    return;
  }
  if (bx >= 256) {
    // ---- W1 plain bf16 conversion
    const int idx = (bx - 256) * 256 + tid;
    f32x4 v = *(const f32x4*)(w1 + (size_t)idx * 4);
    uint2 p;
    p.x = pack2(v.x, v.y);
    p.y = pack2(v.z, v.w);
    *(uint2*)(w1b + (size_t)idx * 4) = p;
    return;
  }
  // ---- route branch
  __shared__ int s_lpos[NB];
  __shared__ int s_lbase[NB];
  __shared__ int s_b[256];
  const int base = bx * 256;
  const int token = base + tid;
  if (tid < NB) s_lpos[tid] = 0;
  __syncthreads();
  const int b = b_seq[token];
  s_b[tid] = b;
  int my = 0;
  if (b > 0) my = atomicAdd(&s_lpos[b - 1], 1);
  __syncthreads();
  if (tid < NB) s_lbase[tid] = atomicAdd(&counts[tid], s_lpos[tid]);
  __syncthreads();
  if (b > 0) lists[(b - 1) * TOK + s_lbase[b - 1] + my] = (ushort_t)token;
  const u32x4 z = (u32x4){0u, 0u, 0u, 0u};
  #pragma unroll 4
  for (int it = 0; it < 64; ++it) {
    int flat = it * 256 + tid;
    int tl = flat >> 6;
    int j = flat & 63;
    if (s_b[tl] == 0) out16[(size_t)(base + tl) * 64 + j] = z;
  }
}

// ---------------- kernel 1: hybrid FFN + LN (spill-free W2-in-regs) --------
// Cycle model (rounds 3-7): MFMA floor ~26us; LDS-pipe floor was ~74us at
// round-5 traffic (112 b128 + 32KB DMA per chunk per block). W2 direct from
// L2 lowers the LDS floor to ~52us. Round 7 proved the mechanism (conflicts
// 5.05M->1.68M) but spilled (+41MB WRITE): TWO reg buffers live across
// sched_barrier-fenced barriers. Fix: SINGLE W2 reg buffer with zero
// cross-barrier vmem liveness:
//   iter i: ebar -> w2load(i-1) [FIRST, so its vmcnt wait leaves the newer
//   W1 DMAs in flight] -> issue_w1(i+1) -> g1(i) [covers W2 L2 latency]
//   -> g2(i-1) consumes w2r. Nothing vmem-live across ebar.
// Regs: xfrag 32 + w2r 16 + yacc 32 AGPR + ~25 misc ~ 105 <= 128 cap.
// Block = 8 waves (512 thr), M=64 tokens, 32 chunks of F=32.
//  GEMM1 wave (fi=wv&1, mq=wv>>1): 16 tok x 16 f.
//  GEMM2 wave (dq=wv&3, mh=wv>>2): 32 tok x 64 d, W2 frags from global.
// LDS reads/chunk: 80 b128 (round 5: 112); DMA writes 16KB (was 32KB).
__global__ __launch_bounds__(512, 4) void ffn_kernel(
    const float* __restrict__ x,
    const ushort_t* __restrict__ w1b_all, const float* __restrict__ b1,
    const ushort_t* __restrict__ w2f_all, const float* __restrict__ b2,
    const float* __restrict__ gamma, const float* __restrict__ beta,
    const int* __restrict__ counts, const ushort_t* __restrict__ lists,
    float* __restrict__ out)
{
  const int id = blockIdx.x;
  const int slot = id & 7;            // XCD affinity: branch n -> XCDs {2n,2n+1}
  const int n = slot >> 1;
  const int tile = ((id >> 3) << 1) + (slot & 1);
  const int cnt = counts[n];
  const int tile0 = tile * 64;
  if (tile0 >= cnt) return;           // block-uniform exit before any barrier
  const int mvalid = min(64, cnt - tile0);

  __shared__ __align__(16) ushort_t sW1[2][8192];   // 2 x 16KB (32f x 256k)
  __shared__ __align__(16) ushort_t sH[2][64][40];  // H double-buffer
  __shared__ ushort_t sB1[DF];        // b1 as bf16 (exact for b1==0)
  __shared__ int s_idx[64];
  __shared__ float s_ps[4][64];
  __shared__ float s_pq[4][64];
  __shared__ float s_mu[64];
  __shared__ float s_rs[64];
  // total ~47 KB

  ushort_t (*sX)[256] = (ushort_t (*)[256])&sW1[0][0];  // prologue alias 32KB

  const int tid  = threadIdx.x;
  const int wv   = tid >> 6;          // 0..7
  const int lane = tid & 63;
  const int q    = lane >> 4;
  const int lc   = lane & 15;
  const int fi   = wv & 1;            // GEMM1: f-sub (16 of the 32-chunk)
  const int mq   = wv >> 1;           // GEMM1: token quarter (16 rows)
  const int dq   = wv & 3;            // GEMM2: d-quarter (64 cols)
  const int mh   = wv >> 2;           // GEMM2: token half (32 rows)

  const ushort_t* w1b = w1b_all + (size_t)n * DF * DM;
  const ushort_t* w2f = w2f_all + (size_t)n * 262144;   // 512 KB / branch

  if (tid < 64) {
    int i = tile0 + tid;
    s_idx[tid] = (int)lists[n * TOK + (i < cnt ? i : tile0)];
  }
  if (tid < 256) {
    f32x4 v = *(const f32x4*)(b1 + n * DF + tid * 4);
    uint2 p;
    p.x = pack2(v.x, v.y);
    p.y = pack2(v.z, v.w);
    *(uint2*)(sB1 + tid * 4) = p;
  }
  __syncthreads();                    // B0: s_idx ready

  // ---- stage X tile 64x256 fp32 -> bf16 into sX, 16B-granule XOR swizzle
  #pragma unroll
  for (int it = 0; it < 4; ++it) {
    int flat = it * 512 + tid;
    int r = flat >> 5;                 // 0..63
    int c8 = flat & 31;                // 16B granule (8 bf16)
    const float* xp = x + (size_t)s_idx[r] * DM + c8 * 8;
    f32x4 a = *(const f32x4*)xp;
    f32x4 c = *(const f32x4*)(xp + 4);
    u32x4 p;
    p.x = pack2(a.x, a.y); p.y = pack2(a.z, a.w);
    p.z = pack2(c.x, c.y); p.w = pack2(c.z, c.w);
    *(u32x4*)(&sX[r][(c8 ^ (r & 31)) * 8]) = p;
  }
  __syncthreads();                    // B1: sX ready

  // ---- X A-frags to regs: this wave's 16 tokens x K=256 (32 VGPR)
  bf16x8 xfrag[8];
  #pragma unroll
  for (int ks = 0; ks < 8; ++ks) {
    int row = mq * 16 + lc;
    int g = (ks * 4 + q) ^ (row & 31);
    xfrag[ks] = *(const bf16x8*)(&sX[row][g * 8]);
  }
  __syncthreads();                    // B2: sX dead, W1 bufs free

  // W1 chunk fc -> sW1[fc&1]: 16 x 1KB segs over 8 waves (2/wave).
  // LDS[r][c] = G[r][c ^ r] (src-side swizzle; matches GEMM1 read).
  auto issue_w1 = [&](int fc) {
    ushort_t* dst = sW1[fc & 1];
    const ushort_t* g1p = w1b + (size_t)(fc * 32) * DM;
    #pragma unroll
    for (int j = 0; j < 2; ++j) {
      int i = wv * 2 + j;              // 0..15
      int s = i * 64 + lane;
      int r1 = s >> 5, cp1 = s & 31;
      dma16(g1p + (size_t)r1 * DM + (size_t)(cp1 ^ r1) * 8, dst + i * 512);
    }
  };
  // W2 chunk fc -> this wave's 4 frags (4KB, coalesced dwordx4 from L2)
  auto w2load = [&](int fc, bf16x8 (&w2r)[4]) {
    const ushort_t* p = w2f + (size_t)(fc * 4 + dq) * 2048 + lane * 8;
    #pragma unroll
    for (int di = 0; di < 4; ++di)
      w2r[di] = *(const bf16x8*)(p + di * 512);
  };

  f32x4 yacc[2][4];       // [mi2][di]: 32 tok x 64 d (32 AGPR)
  #pragma unroll
  for (int mi2 = 0; mi2 < 2; ++mi2)
    #pragma unroll
    for (int di = 0; di < 4; ++di)
      yacc[mi2][di] = (f32x4){0.f, 0.f, 0.f, 0.f};

  const int r1row = fi * 16 + lc;     // GEMM1 W1 local row (0..31)

  auto ebar = [&]() {
    __builtin_amdgcn_sched_barrier(0);
    __builtin_amdgcn_s_waitcnt(0x0070);     // vmcnt(0) lgkmcnt(0)
    __builtin_amdgcn_s_barrier();
    __builtin_amdgcn_sched_barrier(0);
  };
  auto g1 = [&](int fc) {
    const ushort_t* w1row = sW1[fc & 1] + r1row * 256;
    const float b1v = bf2f(sB1[fc * 32 + fi * 16 + lc]);
    f32x4 ha = (f32x4){0.f, 0.f, 0.f, 0.f};
    f32x4 hb = (f32x4){0.f, 0.f, 0.f, 0.f};
    __builtin_amdgcn_s_setprio(1);
    #pragma unroll
    for (int ks = 0; ks < 4; ++ks) {
      int cpa = ((2 * ks) * 4 + q) ^ r1row;
      int cpb = ((2 * ks + 1) * 4 + q) ^ r1row;
      bf16x8 bfa = *(const bf16x8*)(w1row + cpa * 8);
      bf16x8 bfb = *(const bf16x8*)(w1row + cpb * 8);
      ha = __builtin_amdgcn_mfma_f32_16x16x32_bf16(xfrag[2 * ks],     bfa, ha, 0, 0, 0);
      hb = __builtin_amdgcn_mfma_f32_16x16x32_bf16(xfrag[2 * ks + 1], bfb, hb, 0, 0, 0);
    }
    __builtin_amdgcn_s_setprio(0);
    #pragma unroll
    for (int r4 = 0; r4 < 4; ++r4) {
      float v = ha[r4] + hb[r4] + b1v;
      v = (v > 0.f) ? v : (__expf(v) - 1.f);
      sH[fc & 1][mq * 16 + q * 4 + r4][fi * 16 + lc] = f2bf(v);
    }
  };
  auto g2_comp = [&](int fc, bf16x8 (&w2r)[4]) {
    const int rb = fc & 1;
    bf16x8 af0 = *(const bf16x8*)(&sH[rb][mh * 32 + lc][q * 8]);
    bf16x8 af1 = *(const bf16x8*)(&sH[rb][mh * 32 + 16 + lc][q * 8]);
    __builtin_amdgcn_s_setprio(1);
    #pragma unroll
    for (int di = 0; di < 4; ++di) {
      yacc[0][di] = __builtin_amdgcn_mfma_f32_16x16x32_bf16(af0, w2r[di], yacc[0][di], 0, 0, 0);
      yacc[1][di] = __builtin_amdgcn_mfma_f32_16x16x32_bf16(af1, w2r[di], yacc[1][di], 0, 0, 0);
    }
    __builtin_amdgcn_s_setprio(0);
  };

  bf16x8 w2r[4];          // SINGLE buffer: loaded and consumed in the same
                          // iteration -> no vmem value live across ebar.

  // iter i: GEMM1(i) [i<32], GEMM2(i-1) [i>=1]. W2(i-1) frags loaded at the
  // top of iter i (before the W1 DMA, so the compiler's vmcnt wait for w2r
  // completes only the 4 oldest loads and leaves the DMAs in flight).
  issue_w1(0);
  #pragma unroll 1
  for (int i = 0; i <= 32; ++i) {
    ebar();                            // drains W1(i) DMA; sH(i-1) visible
    if (i >= 1) w2load(i - 1, w2r);    // oldest vmem ops this iter
    if (i < 31) issue_w1(i + 1);       // newer; stays in flight across g2
    if (i < 32) g1(i);                 // covers w2load's L2 latency
    if (i >= 1) g2_comp(i - 1, w2r);
  }

  // ================= epilogue: +b2, LN stats, gamma/beta, store =============
  __syncthreads();
  float b2v[4], gv[4], bv[4];
  #pragma unroll
  for (int di = 0; di < 4; ++di) {
    int dcol = n * DM + dq * 64 + di * 16 + lc;
    b2v[di] = b2[dcol];
    gv[di]  = gamma[dcol];
    bv[di]  = beta[dcol];
  }
  #pragma unroll
  for (int mi2 = 0; mi2 < 2; ++mi2)
    #pragma unroll
    for (int di = 0; di < 4; ++di)
      #pragma unroll
      for (int r4 = 0; r4 < 4; ++r4)
        yacc[mi2][di][r4] += b2v[di];

  #pragma unroll
  for (int mi2 = 0; mi2 < 2; ++mi2) {
    #pragma unroll
    for (int r4 = 0; r4 < 4; ++r4) {
      float s = 0.f, sq = 0.f;
      #pragma unroll
      for (int di = 0; di < 4; ++di) {
        float v = yacc[mi2][di][r4];
        s += v; sq += v * v;
      }
      #pragma unroll
      for (int off = 1; off < 16; off <<= 1) {
        s  += __shfl_xor(s, off, 64);
        sq += __shfl_xor(sq, off, 64);
      }
      if (lc == 0) {
        int tok = mh * 32 + mi2 * 16 + q * 4 + r4;
        s_ps[dq][tok] = s;
        s_pq[dq][tok] = sq;
      }
    }
  }
  __syncthreads();
  if (tid < 64) {
    float s  = s_ps[0][tid] + s_ps[1][tid] + s_ps[2][tid] + s_ps[3][tid];
    float sq = s_pq[0][tid] + s_pq[1][tid] + s_pq[2][tid] + s_pq[3][tid];
    float mu = s * (1.f / 256.f);
    float var = fmaxf(sq * (1.f / 256.f) - mu * mu, 0.f);
    s_mu[tid] = mu;
    s_rs[tid] = rsqrtf(var + 1e-12f);
  }
  __syncthreads();

  #pragma unroll
  for (int mi2 = 0; mi2 < 2; ++mi2) {
    #pragma unroll
    for (int r4 = 0; r4 < 4; ++r4) {
      int tok = mh * 32 + mi2 * 16 + q * 4 + r4;
      if (tok < mvalid) {
        float mu = s_mu[tok], rs = s_rs[tok];
        size_t rowbase = (size_t)s_idx[tok] * DM + dq * 64;
        #pragma unroll
        for (int di = 0; di < 4; ++di) {
          float v = (yacc[mi2][di][r4] - mu) * rs * gv[di] + bv[di];
          out[rowbase + di * 16 + lc] = v;
        }
      }
    }
  }
}

extern "C" void kernel_launch(void* const* d_in, const int* in_sizes, int n_in,
                              void* d_out, int out_size, void* d_ws, size_t ws_size,
                              hipStream_t stream) {
  const float* x     = (const float*)d_in[0];
  const int*   b_seq = (const int*)d_in[1];
  const float* w1    = (const float*)d_in[2];
  const float* b1    = (const float*)d_in[3];
  const float* w2    = (const float*)d_in[4];
  const float* b2    = (const float*)d_in[5];
  const float* gamma = (const float*)d_in[6];
  const float* beta  = (const float*)d_in[7];
  float* out = (float*)d_out;

  int* counts = (int*)d_ws;
  ushort_t* lists = (ushort_t*)((char*)d_ws + 256);                 // 512 KB
  ushort_t* w1b = (ushort_t*)((char*)d_ws + 256 + 512 * 1024);      // 2 MB
  ushort_t* w2fb = w1b + (size_t)NB * DF * DM;                      // 2 MB

  hipMemsetAsync(counts, 0, 256, stream);
  // blocks [0,256): route; [256,1280): W1 bf16; [1280,1792): W2 frag layout
  hipLaunchKernelGGL(prep_route_kernel, dim3(1792), dim3(256), 0, stream,
                     w1, w2, w1b, w2fb, b_seq, counts, lists, (u32x4*)d_out);
  // 1024 tiles/branch capacity: covers any branch imbalance up to 65536
  hipLaunchKernelGGL(ffn_kernel, dim3(4096), dim3(512), 0, stream,
                     x, w1b, b1, w2fb, b2, gamma, beta, counts, lists, out);
}